// Round 1
// baseline (38.932 us; speedup 1.0000x reference)
//
#include <hip/hip_runtime.h>

// DQN graph-embedding network, MI355X.
// B=16, A=256, UNITS=HID=64, T=3. All fp32 (no fp32 MFMA on CDNA4 -> vector ALU).
//
// Math restructuring (exact up to fp reassociation):
//   e1[i,j]   = cs_i * W0_j
//   e3 @ W2   = (pos_i * P2_j + neg_i * N2_j)/A,  P2 = relu(W3)@W2, N2 = min(W3,0)@W2
//   agg[i,m]  = colsum(emb)[m] - sum_{k in zeros(i)} emb[k,m]   (zeros tracked by bitmask)
//   e2[i,j]   = (1/A) * (S - Z_i) @ W1
// so each T-iteration only needs the 64-vector e2c = (S/A)@W1 plus rare per-row corrections.

#define NB 16
#define NA 256
#define NU 64

__device__ __forceinline__ float reluf(float v) { return fmaxf(v, 0.f); }

// ---------------- K0: per-row weight stats (pos/neg sums + zero bitmask) ----------
// grid 64 x 256 threads; 4 threads per row, 64 cols each.
__global__ __launch_bounds__(256) void k0_stats(const float* __restrict__ x,
                                                float* __restrict__ pos,
                                                float* __restrict__ neg,
                                                unsigned long long* __restrict__ zmask)
{
    int t = threadIdx.x;
    int rid = blockIdx.x * 64 + (t >> 2);   // global row id, 0..4095
    int sub = t & 3;
    int b = rid >> 8;
    int i = rid & 255;
    const float* row = x + ((size_t)b * 258 + 2 + (size_t)i) * 256 + sub * 64;
    float p = 0.f, n = 0.f;
    unsigned long long zm = 0ull;
    #pragma unroll
    for (int c = 0; c < 64; c += 4) {
        float4 v = *(const float4*)(row + c);
        p += fmaxf(v.x, 0.f) + fmaxf(v.y, 0.f) + fmaxf(v.z, 0.f) + fmaxf(v.w, 0.f);
        n += fminf(v.x, 0.f) + fminf(v.y, 0.f) + fminf(v.z, 0.f) + fminf(v.w, 0.f);
        if (v.x == 0.f) zm |= 1ull << (c + 0);
        if (v.y == 0.f) zm |= 1ull << (c + 1);
        if (v.z == 0.f) zm |= 1ull << (c + 2);
        if (v.w == 0.f) zm |= 1ull << (c + 3);
    }
    zmask[(size_t)rid * 4 + sub] = zm;
    p += __shfl_xor(p, 1); p += __shfl_xor(p, 2);
    n += __shfl_xor(n, 1); n += __shfl_xor(n, 2);
    if (sub == 0) { pos[rid] = p; neg[rid] = n; }
}

// ---------------- K1: T=3 embedding iterations, one block per batch ---------------
// 1024 threads: thread t owns row t>>2, cols (t&3)*16 .. +15, held in registers.
// Column sums via wave shuffles (stride 4/8/16/32) -> LDS partials -> e2c.
// emb written to global ws each iteration (needed by zero-correction path + K2).
__global__ __launch_bounds__(1024) void k1_embed(
    const float* __restrict__ x,
    const float* __restrict__ W0, const float* __restrict__ W1,
    const float* __restrict__ W2, const float* __restrict__ W3,
    const float* __restrict__ pos, const float* __restrict__ neg,
    const unsigned long long* __restrict__ zmask,
    float* __restrict__ embg)
{
    __shared__ float W1s[64 * 64];
    __shared__ float poss[256], negs[256], css[256];
    __shared__ float W0s[64], P2s[64], N2s[64], Ssh[64], e2c[64];
    __shared__ float wpart[16 * 64];
    __shared__ int zrow[256];
    __shared__ unsigned long long zms[1024];

    const float invA = 1.0f / 256.0f;
    int b = blockIdx.x;
    int t = threadIdx.x;

    for (int idx = t; idx < 4096; idx += 1024) W1s[idx] = W1[idx];
    if (t < 256) {
        poss[t] = pos[b * 256 + t];
        negs[t] = neg[b * 256 + t];
        css[t]  = x[(size_t)b * 258 * 256 + t];       // cur_sol row
    }
    zms[t] = zmask[(size_t)b * 1024 + t];
    if (t < 64) {
        W0s[t] = W0[t];
        float pa = 0.f, na = 0.f;
        for (int m = 0; m < 64; ++m) {
            float w3 = W3[m];
            float w2 = W2[m * 64 + t];
            pa += fmaxf(w3, 0.f) * w2;
            na += fminf(w3, 0.f) * w2;
        }
        P2s[t] = pa; N2s[t] = na;
        e2c[t] = 0.f;
    }
    __syncthreads();
    if (t < 256)
        zrow[t] = (zms[4 * t] | zms[4 * t + 1] | zms[4 * t + 2] | zms[4 * t + 3]) != 0ull;
    __syncthreads();

    int row = t >> 2;
    int sub = t & 3;
    int jb  = sub * 16;
    int w   = t >> 6;
    int l   = t & 63;
    float cs_i = css[row], p_i = poss[row], n_i = negs[row];
    float basev[16];
    #pragma unroll
    for (int q = 0; q < 16; ++q) {
        int j = jb + q;
        basev[q] = cs_i * W0s[j] + (p_i * P2s[j] + n_i * N2s[j]) * invA;
    }
    float* myg = embg + (size_t)b * (NA * NU) + row * 64 + jb;

    for (int iter = 0; iter < 3; ++iter) {
        float v[16];
        if (iter == 0) {
            #pragma unroll
            for (int q = 0; q < 16; ++q) v[q] = reluf(basev[q]);
        } else {
            #pragma unroll
            for (int q = 0; q < 16; ++q) v[q] = basev[q] + e2c[jb + q];
            if (zrow[row]) {     // exact correction for adjacency zeros (rare/never)
                const float* eb = embg + (size_t)b * (NA * NU);
                for (int wd = 0; wd < 4; ++wd) {
                    unsigned long long zm = zms[4 * row + wd];
                    while (zm) {
                        int k = wd * 64 + __builtin_ctzll(zm);
                        zm &= zm - 1;
                        for (int q = 0; q < 16; ++q) {
                            float acc = 0.f;
                            for (int m = 0; m < 64; ++m)
                                acc += eb[k * 64 + m] * W1s[m * 64 + jb + q];
                            v[q] -= acc * invA;
                        }
                    }
                }
            }
            #pragma unroll
            for (int q = 0; q < 16; ++q) v[q] = reluf(v[q]);
        }
        __syncthreads();                      // all reads of previous emb complete
        #pragma unroll
        for (int q = 0; q < 16; q += 4)
            *(float4*)(myg + q) = make_float4(v[q], v[q + 1], v[q + 2], v[q + 3]);

        if (iter < 2) {
            // wave-level column sums: lanes differing in bits 2..5 hold the same cols
            #pragma unroll
            for (int q = 0; q < 16; ++q) {
                float s = v[q];
                s += __shfl_xor(s, 4);
                s += __shfl_xor(s, 8);
                s += __shfl_xor(s, 16);
                s += __shfl_xor(s, 32);
                if (l < 4) wpart[w * 64 + jb + q] = s;
            }
            __syncthreads();
            if (t < 64) {
                float s = 0.f;
                for (int ww = 0; ww < 16; ++ww) s += wpart[ww * 64 + t];
                Ssh[t] = s;
            }
            __syncthreads();
            if (t < 64) {
                float acc = 0.f;
                for (int m = 0; m < 64; ++m) acc += Ssh[m] * W1s[m * 64 + t];
                e2c[t] = acc * invA;
            }
            __threadfence_block();
            __syncthreads();
        }
    }
}

// ---------------- K2: head MLPs, 32 rows per block, 8 threads per row -------------
__global__ __launch_bounds__(256) void k2_heads(
    const float* __restrict__ embg,
    const float* __restrict__ aw1, const float* __restrict__ ab1,
    const float* __restrict__ aw2, const float* __restrict__ ab2,
    const float* __restrict__ aw3, const float* __restrict__ ab3,
    const float* __restrict__ vw1, const float* __restrict__ vb1,
    const float* __restrict__ vw2, const float* __restrict__ vb2,
    float* __restrict__ out_a, float* __restrict__ ovv)
{
    __shared__ float aw1s[64 * 64];
    __shared__ float vw1s[64 * 64];
    __shared__ float aw2s[64 * 33];       // stride 33: kills 8-way bank conflict
    __shared__ float embs[32 * 64];
    __shared__ float ab1s[64], vb1s[64], vw2s[64], ab2s[32], aw3s[32];
    __shared__ float ab3s[1], vb2s[1];

    int t = threadIdx.x;
    for (int idx = t; idx < 4096; idx += 256) { aw1s[idx] = aw1[idx]; vw1s[idx] = vw1[idx]; }
    for (int idx = t; idx < 2048; idx += 256) {
        int r = idx >> 5, c = idx & 31;
        aw2s[r * 33 + c] = aw2[idx];
    }
    if (t < 64) { ab1s[t] = ab1[t]; vb1s[t] = vb1[t]; vw2s[t] = vw2[t]; }
    if (t >= 64 && t < 96) { ab2s[t - 64] = ab2[t - 64]; aw3s[t - 64] = aw3[t - 64]; }
    if (t == 96) { ab3s[0] = ab3[0]; vb2s[0] = vb2[0]; }

    int rbase = blockIdx.x * 32;
    for (int idx = t; idx < 2048; idx += 256) embs[idx] = embg[(size_t)rbase * 64 + idx];
    __syncthreads();

    int lr = t >> 3;            // local row 0..31
    int jb = (t & 7) * 8;       // 8 contiguous h1/hv columns
    int rid = rbase + lr;

    float h1[8], hv[8];
    #pragma unroll
    for (int q = 0; q < 8; ++q) { h1[q] = ab1s[jb + q]; hv[q] = vb1s[jb + q]; }

    for (int m = 0; m < 64; ++m) {
        float em = embs[lr * 64 + m];
        const float4 a0 = *(const float4*)&aw1s[m * 64 + jb];
        const float4 a1 = *(const float4*)&aw1s[m * 64 + jb + 4];
        const float4 b0 = *(const float4*)&vw1s[m * 64 + jb];
        const float4 b1 = *(const float4*)&vw1s[m * 64 + jb + 4];
        h1[0] = fmaf(em, a0.x, h1[0]); h1[1] = fmaf(em, a0.y, h1[1]);
        h1[2] = fmaf(em, a0.z, h1[2]); h1[3] = fmaf(em, a0.w, h1[3]);
        h1[4] = fmaf(em, a1.x, h1[4]); h1[5] = fmaf(em, a1.y, h1[5]);
        h1[6] = fmaf(em, a1.z, h1[6]); h1[7] = fmaf(em, a1.w, h1[7]);
        hv[0] = fmaf(em, b0.x, hv[0]); hv[1] = fmaf(em, b0.y, hv[1]);
        hv[2] = fmaf(em, b0.z, hv[2]); hv[3] = fmaf(em, b0.w, hv[3]);
        hv[4] = fmaf(em, b1.x, hv[4]); hv[5] = fmaf(em, b1.y, hv[5]);
        hv[6] = fmaf(em, b1.z, hv[6]); hv[7] = fmaf(em, b1.w, hv[7]);
    }

    float ovp = 0.f;
    #pragma unroll
    for (int q = 0; q < 8; ++q) {
        h1[q] = reluf(h1[q]);
        hv[q] = reluf(hv[q]);
        ovp = fmaf(hv[q], vw2s[jb + q], ovp);
    }
    ovp += __shfl_xor(ovp, 1); ovp += __shfl_xor(ovp, 2); ovp += __shfl_xor(ovp, 4);

    float h2p[32];
    #pragma unroll
    for (int j2 = 0; j2 < 32; ++j2) h2p[j2] = 0.f;
    #pragma unroll
    for (int q = 0; q < 8; ++q) {
        float h = h1[q];
        int r = jb + q;
        #pragma unroll
        for (int j2 = 0; j2 < 32; ++j2) h2p[j2] = fmaf(h, aw2s[r * 33 + j2], h2p[j2]);
    }
    #pragma unroll
    for (int j2 = 0; j2 < 32; ++j2) {
        float s = h2p[j2];
        s += __shfl_xor(s, 1); s += __shfl_xor(s, 2); s += __shfl_xor(s, 4);
        h2p[j2] = s;
    }

    if ((t & 7) == 0) {
        float oa = ab3s[0];
        #pragma unroll
        for (int j2 = 0; j2 < 32; ++j2)
            oa = fmaf(reluf(h2p[j2] + ab2s[j2]), aw3s[j2], oa);
        out_a[rid] = oa;
        ovv[rid]   = ovp + vb2s[0];
    }
}

// ---------------- K3: deterministic per-batch reductions + final combine ----------
__global__ __launch_bounds__(256) void k3_final(const float* __restrict__ x,
                                                const float* __restrict__ out_a,
                                                const float* __restrict__ ovv,
                                                float* __restrict__ out)
{
    __shared__ float sa[256], sv[256];
    int b = blockIdx.x, t = threadIdx.x;
    float oa = out_a[b * 256 + t];
    sa[t] = oa;
    sv[t] = ovv[b * 256 + t];
    __syncthreads();
    for (int s = 128; s > 0; s >>= 1) {
        if (t < s) { sa[t] += sa[t + s]; sv[t] += sv[t + s]; }
        __syncthreads();
    }
    float mask = x[((size_t)b * 258 + 1) * 256 + t];
    out[b * 256 + t] = sv[0] + oa - sa[0] + mask * 10.0f;
}

extern "C" void kernel_launch(void* const* d_in, const int* in_sizes, int n_in,
                              void* d_out, int out_size, void* d_ws, size_t ws_size,
                              hipStream_t stream)
{
    (void)in_sizes; (void)n_in; (void)out_size; (void)ws_size;
    const float* x   = (const float*)d_in[0];
    const float* W0  = (const float*)d_in[1];
    const float* W1  = (const float*)d_in[2];
    const float* W2  = (const float*)d_in[3];
    const float* W3  = (const float*)d_in[4];
    const float* aw1 = (const float*)d_in[5];
    const float* ab1 = (const float*)d_in[6];
    const float* aw2 = (const float*)d_in[7];
    const float* ab2 = (const float*)d_in[8];
    const float* aw3 = (const float*)d_in[9];
    const float* ab3 = (const float*)d_in[10];
    const float* vw1 = (const float*)d_in[11];
    const float* vb1 = (const float*)d_in[12];
    const float* vw2 = (const float*)d_in[13];
    const float* vb2 = (const float*)d_in[14];

    float* ws   = (float*)d_ws;
    float* pos  = ws;                       //  4096 floats
    float* neg  = ws + 4096;                //  4096
    float* oaw  = ws + 8192;                //  4096
    float* ovw  = ws + 12288;               //  4096
    float* embg = ws + 16384;               //  16*256*64 = 262144
    unsigned long long* zmask = (unsigned long long*)(ws + 16384 + 262144);  // 16384 u64

    k0_stats<<<64, 256, 0, stream>>>(x, pos, neg, zmask);
    k1_embed<<<16, 1024, 0, stream>>>(x, W0, W1, W2, W3, pos, neg, zmask, embg);
    k2_heads<<<128, 256, 0, stream>>>(embg, aw1, ab1, aw2, ab2, aw3, ab3,
                                      vw1, vb1, vw2, vb2, oaw, ovw);
    k3_final<<<16, 256, 0, stream>>>(x, oaw, ovw, (float*)d_out);
}

// Round 2
// 35.627 us; speedup vs baseline: 1.0928x; 1.0928x over previous
//
#include <hip/hip_runtime.h>

// DQN graph-embedding network, MI355X. B=16, A=256, UNITS=HID=64, T=3, fp32.
//
// Algebra (exact up to fp reassociation):
//   base[i,j] = cs_i*W0_j + (pos_i*P2_j + neg_i*N2_j)/A,  P2=relu(W3)@W2, N2=min(W3,0)@W2
//   emb_t[i,j] = relu(base[i,j] + c_t[j]),  c_{t+1} = (colsum(emb_t)/A) @ W1,  c_0 = 0
//   (valid when no adjacency zeros; per-batch dirty flag falls back to exact
//    materialized-emb path with per-row corrections.)
// KA: stats + c2 (16 blocks x 1024). KB: heads + block partials (128 x 256).
// KC: final combine (16 x 256).

#define NB 16
#define NA 256
#define NU 64

__device__ __forceinline__ float reluf(float v) { return fmaxf(v, 0.f); }

// ---------------- KA: stats + embedding recurrence (one block per batch) ----------
__global__ __launch_bounds__(1024) void ka_embed(
    const float* __restrict__ x,
    const float* __restrict__ W0, const float* __restrict__ W1,
    const float* __restrict__ W2, const float* __restrict__ W3,
    float* __restrict__ posg, float* __restrict__ negg,
    float* __restrict__ c2g, float* __restrict__ P2g, float* __restrict__ N2g,
    int* __restrict__ flagg, float* __restrict__ embg)
{
    __shared__ float W1s[64 * 64];
    __shared__ float embL[256 * 68];          // only used on dirty (zero-weight) path
    __shared__ float wpart[16 * 64], npart[16 * 64];
    __shared__ float poss[256], negs[256], css[256];
    __shared__ float W0s[64], P2s[64], N2s[64], Ssh[64], e2c[64];
    __shared__ int   zrow[256];
    __shared__ unsigned long long zms[1024];
    __shared__ int sdirty;

    const float invA = 1.0f / 256.0f;
    int b = blockIdx.x;
    int t = threadIdx.x;
    int r = t >> 2;           // row 0..255 (4 threads per row)
    int sub = t & 3;
    int jb = sub * 16;

    // --- stats: pos/neg sums + zero bitmask for this thread's 64 columns ---
    {
        const float* rowp = x + ((size_t)b * 258 + 2 + (size_t)r) * 256 + sub * 64;
        float p = 0.f, n = 0.f;
        unsigned long long zm = 0ull;
        #pragma unroll
        for (int c = 0; c < 64; c += 4) {
            float4 v = *(const float4*)(rowp + c);
            p += fmaxf(v.x, 0.f) + fmaxf(v.y, 0.f) + fmaxf(v.z, 0.f) + fmaxf(v.w, 0.f);
            n += fminf(v.x, 0.f) + fminf(v.y, 0.f) + fminf(v.z, 0.f) + fminf(v.w, 0.f);
            if (v.x == 0.f) zm |= 1ull << (c + 0);
            if (v.y == 0.f) zm |= 1ull << (c + 1);
            if (v.z == 0.f) zm |= 1ull << (c + 2);
            if (v.w == 0.f) zm |= 1ull << (c + 3);
        }
        zms[t] = zm;
        p += __shfl_xor(p, 1); p += __shfl_xor(p, 2);
        n += __shfl_xor(n, 1); n += __shfl_xor(n, 2);
        if (sub == 0) { poss[r] = p; negs[r] = n; }
    }
    if (t < 256) css[t] = x[(size_t)b * 258 * 256 + t];
    if (t == 0) sdirty = 0;

    for (int idx = t; idx < 4096; idx += 1024) W1s[idx] = W1[idx];

    // --- P2/N2 partials (16 m-groups x 64 cols) ---
    {
        int j = t & 63, mg = t >> 6;
        float pa = 0.f, na = 0.f;
        #pragma unroll
        for (int k = 0; k < 4; ++k) {
            int m = mg * 4 + k;
            float w3 = W3[m];
            float w2 = W2[m * 64 + j];
            pa = fmaf(fmaxf(w3, 0.f), w2, pa);
            na = fmaf(fminf(w3, 0.f), w2, na);
        }
        wpart[mg * 64 + j] = pa;
        npart[mg * 64 + j] = na;
    }
    __syncthreads();

    if (t < 256) {
        int zr = (zms[4 * t] | zms[4 * t + 1] | zms[4 * t + 2] | zms[4 * t + 3]) != 0ull;
        zrow[t] = zr;
        if (zr) sdirty = 1;                 // benign race, all write 1
        posg[b * 256 + t] = poss[t];
        negg[b * 256 + t] = negs[t];
    }
    if (t < 64) {
        float P2 = 0.f, N2 = 0.f;
        #pragma unroll
        for (int g = 0; g < 16; ++g) { P2 += wpart[g * 64 + t]; N2 += npart[g * 64 + t]; }
        P2s[t] = P2; N2s[t] = N2; W0s[t] = W0[t];
        P2g[t] = P2; N2g[t] = N2;           // all blocks write identical values
    }
    __syncthreads();

    float cs_i = css[r], p_i = poss[r], n_i = negs[r];
    float base[16];
    #pragma unroll
    for (int q = 0; q < 16; ++q)
        base[q] = fmaf(cs_i, W0s[jb + q], (p_i * P2s[jb + q] + n_i * N2s[jb + q]) * invA);

    int dirty = sdirty;

    if (!dirty) {
        // ---------------- fast path: 2 colsum->matvec rounds, no emb materialization
        #pragma unroll
        for (int iter = 0; iter < 2; ++iter) {
            float v[16];
            #pragma unroll
            for (int q = 0; q < 16; ++q)
                v[q] = reluf(iter == 0 ? base[q] : base[q] + e2c[jb + q]);
            // colsum over this wave's 16 rows (lane bits 2..5), then LDS partials
            #pragma unroll
            for (int q = 0; q < 16; ++q) {
                float s = v[q];
                s += __shfl_xor(s, 4); s += __shfl_xor(s, 8);
                s += __shfl_xor(s, 16); s += __shfl_xor(s, 32);
                if ((t & 63) < 4) wpart[(t >> 6) * 64 + jb + q] = s;
            }
            __syncthreads();
            if (t < 64) {
                float S = 0.f;
                #pragma unroll
                for (int w = 0; w < 16; ++w) S += wpart[w * 64 + t];
                Ssh[t] = S;                               // same-wave LDS exchange
                float c = 0.f;
                for (int m = 0; m < 64; ++m) c = fmaf(Ssh[m], W1s[m * 64 + t], c);
                c *= invA;
                if (iter == 0) e2c[t] = c;
                else           c2g[b * 64 + t] = c;       // c2: all KB needs
            }
            __syncthreads();
        }
        if (t == 0) flagg[b] = 0;
    } else {
        // ---------------- exact slow path: materialize emb in LDS w/ corrections
        for (int iter = 0; iter < 3; ++iter) {
            float v[16];
            if (iter == 0) {
                #pragma unroll
                for (int q = 0; q < 16; ++q) v[q] = reluf(base[q]);
            } else {
                #pragma unroll
                for (int q = 0; q < 16; ++q) v[q] = base[q] + e2c[jb + q];
                if (zrow[r]) {
                    for (int wd = 0; wd < 4; ++wd) {
                        unsigned long long zm = zms[4 * r + wd];
                        while (zm) {
                            int k = wd * 64 + __builtin_ctzll(zm);
                            zm &= zm - 1;
                            #pragma unroll
                            for (int q = 0; q < 16; ++q) {
                                float acc = 0.f;
                                for (int m = 0; m < 64; ++m)
                                    acc = fmaf(embL[k * 68 + m], W1s[m * 64 + jb + q], acc);
                                v[q] -= acc * invA;
                            }
                        }
                    }
                }
                #pragma unroll
                for (int q = 0; q < 16; ++q) v[q] = reluf(v[q]);
            }
            __syncthreads();                  // old-emb reads done
            #pragma unroll
            for (int q = 0; q < 16; q += 4)
                *(float4*)&embL[r * 68 + jb + q] =
                    make_float4(v[q], v[q + 1], v[q + 2], v[q + 3]);
            if (iter < 2) {
                #pragma unroll
                for (int q = 0; q < 16; ++q) {
                    float s = v[q];
                    s += __shfl_xor(s, 4); s += __shfl_xor(s, 8);
                    s += __shfl_xor(s, 16); s += __shfl_xor(s, 32);
                    if ((t & 63) < 4) wpart[(t >> 6) * 64 + jb + q] = s;
                }
                __syncthreads();
                if (t < 64) {
                    float S = 0.f;
                    #pragma unroll
                    for (int w = 0; w < 16; ++w) S += wpart[w * 64 + t];
                    Ssh[t] = S;
                    float c = 0.f;
                    for (int m = 0; m < 64; ++m) c = fmaf(Ssh[m], W1s[m * 64 + t], c);
                    e2c[t] = c * invA;
                }
                __syncthreads();
            } else {
                __syncthreads();
                for (int idx = t; idx < 16384; idx += 1024)
                    embg[(size_t)b * 16384 + idx] = embL[(idx >> 6) * 68 + (idx & 63)];
            }
        }
        if (t == 0) flagg[b] = 1;
    }
}

// ---------------- KB: heads + per-block partial sums (32 rows/block) --------------
__global__ __launch_bounds__(256) void kb_heads(
    const float* __restrict__ x,
    const float* __restrict__ W0,
    const float* __restrict__ posg, const float* __restrict__ negg,
    const float* __restrict__ c2g, const float* __restrict__ P2g,
    const float* __restrict__ N2g, const int* __restrict__ flagg,
    const float* __restrict__ embg,
    const float* __restrict__ aw1, const float* __restrict__ ab1,
    const float* __restrict__ aw2, const float* __restrict__ ab2,
    const float* __restrict__ aw3, const float* __restrict__ ab3,
    const float* __restrict__ vw1, const float* __restrict__ vb1,
    const float* __restrict__ vw2, const float* __restrict__ vb2,
    float* __restrict__ out_a, float* __restrict__ partA, float* __restrict__ partV)
{
    __shared__ float aw1s[64 * 64];
    __shared__ float vw1s[64 * 64];
    __shared__ float aw2s[64 * 33];
    __shared__ float embs[32 * 65];           // stride 65: conflict-free broadcast
    __shared__ float w0s[64], p2s[64], n2s[64], c2s[64];
    __shared__ float csr[32], pr[32], nr[32];
    __shared__ float ab1s[64], vb1s[64], vw2s[64], ab2s[32], aw3s[32];
    __shared__ float ab3s[1], vb2s[1];
    __shared__ float soa[32], sov[32];

    const float invA = 1.0f / 256.0f;
    int t = threadIdx.x;
    int bb = blockIdx.x >> 3;                 // batch
    int rbase = blockIdx.x * 32;              // global row base

    for (int idx = t; idx < 4096; idx += 256) { aw1s[idx] = aw1[idx]; vw1s[idx] = vw1[idx]; }
    for (int idx = t; idx < 2048; idx += 256)
        aw2s[(idx >> 5) * 33 + (idx & 31)] = aw2[idx];
    if (t < 64) {
        ab1s[t] = ab1[t]; vb1s[t] = vb1[t]; vw2s[t] = vw2[t];
        w0s[t] = W0[t]; p2s[t] = P2g[t]; n2s[t] = N2g[t]; c2s[t] = c2g[bb * 64 + t];
    }
    if (t >= 64 && t < 96) { ab2s[t - 64] = ab2[t - 64]; aw3s[t - 64] = aw3[t - 64]; }
    if (t == 96) { ab3s[0] = ab3[0]; vb2s[0] = vb2[0]; }
    if (t < 32) {
        int i = (blockIdx.x & 7) * 32 + t;
        csr[t] = x[(size_t)bb * 258 * 256 + i];
        pr[t]  = posg[rbase + t];
        nr[t]  = negg[rbase + t];
    }
    int flag = flagg[bb];
    __syncthreads();

    if (flag == 0) {
        #pragma unroll
        for (int k = 0; k < 8; ++k) {
            int idx = k * 256 + t;
            int i = idx >> 6, j = idx & 63;
            embs[i * 65 + j] = reluf(fmaf(csr[i], w0s[j],
                               (pr[i] * p2s[j] + nr[i] * n2s[j]) * invA) + c2s[j]);
        }
    } else {
        #pragma unroll
        for (int k = 0; k < 8; ++k) {
            int idx = k * 256 + t;
            embs[(idx >> 6) * 65 + (idx & 63)] = embg[(size_t)rbase * 64 + idx];
        }
    }
    __syncthreads();

    int lr = t >> 3;
    int jb = (t & 7) * 8;

    float h1[8], hv[8];
    #pragma unroll
    for (int q = 0; q < 8; ++q) { h1[q] = ab1s[jb + q]; hv[q] = vb1s[jb + q]; }

    for (int m = 0; m < 64; ++m) {
        float em = embs[lr * 65 + m];
        const float4 a0 = *(const float4*)&aw1s[m * 64 + jb];
        const float4 a1 = *(const float4*)&aw1s[m * 64 + jb + 4];
        const float4 b0 = *(const float4*)&vw1s[m * 64 + jb];
        const float4 b1 = *(const float4*)&vw1s[m * 64 + jb + 4];
        h1[0] = fmaf(em, a0.x, h1[0]); h1[1] = fmaf(em, a0.y, h1[1]);
        h1[2] = fmaf(em, a0.z, h1[2]); h1[3] = fmaf(em, a0.w, h1[3]);
        h1[4] = fmaf(em, a1.x, h1[4]); h1[5] = fmaf(em, a1.y, h1[5]);
        h1[6] = fmaf(em, a1.z, h1[6]); h1[7] = fmaf(em, a1.w, h1[7]);
        hv[0] = fmaf(em, b0.x, hv[0]); hv[1] = fmaf(em, b0.y, hv[1]);
        hv[2] = fmaf(em, b0.z, hv[2]); hv[3] = fmaf(em, b0.w, hv[3]);
        hv[4] = fmaf(em, b1.x, hv[4]); hv[5] = fmaf(em, b1.y, hv[5]);
        hv[6] = fmaf(em, b1.z, hv[6]); hv[7] = fmaf(em, b1.w, hv[7]);
    }

    float ovp = 0.f;
    #pragma unroll
    for (int q = 0; q < 8; ++q) {
        h1[q] = reluf(h1[q]);
        hv[q] = reluf(hv[q]);
        ovp = fmaf(hv[q], vw2s[jb + q], ovp);
    }
    ovp += __shfl_xor(ovp, 1); ovp += __shfl_xor(ovp, 2); ovp += __shfl_xor(ovp, 4);

    float h2p[32];
    #pragma unroll
    for (int j2 = 0; j2 < 32; ++j2) h2p[j2] = 0.f;
    #pragma unroll
    for (int q = 0; q < 8; ++q) {
        float h = h1[q];
        int rr = jb + q;
        #pragma unroll
        for (int j2 = 0; j2 < 32; ++j2) h2p[j2] = fmaf(h, aw2s[rr * 33 + j2], h2p[j2]);
    }
    #pragma unroll
    for (int j2 = 0; j2 < 32; ++j2) {
        float s = h2p[j2];
        s += __shfl_xor(s, 1); s += __shfl_xor(s, 2); s += __shfl_xor(s, 4);
        h2p[j2] = s;
    }

    if ((t & 7) == 0) {
        float oa = ab3s[0];
        #pragma unroll
        for (int j2 = 0; j2 < 32; ++j2)
            oa = fmaf(reluf(h2p[j2] + ab2s[j2]), aw3s[j2], oa);
        out_a[rbase + lr] = oa;
        soa[lr] = oa;
        sov[lr] = ovp + vb2s[0];
    }
    __syncthreads();
    if (t < 32) {
        float a = soa[t], v = sov[t];
        a += __shfl_xor(a, 1); a += __shfl_xor(a, 2); a += __shfl_xor(a, 4);
        a += __shfl_xor(a, 8); a += __shfl_xor(a, 16);
        v += __shfl_xor(v, 1); v += __shfl_xor(v, 2); v += __shfl_xor(v, 4);
        v += __shfl_xor(v, 8); v += __shfl_xor(v, 16);
        if (t == 0) { partA[blockIdx.x] = a; partV[blockIdx.x] = v; }
    }
}

// ---------------- KC: final combine ----------------------------------------------
__global__ __launch_bounds__(256) void kc_final(const float* __restrict__ x,
                                                const float* __restrict__ out_a,
                                                const float* __restrict__ partA,
                                                const float* __restrict__ partV,
                                                float* __restrict__ out)
{
    int b = blockIdx.x, t = threadIdx.x;
    float oa = out_a[b * 256 + t];
    float sA = 0.f, sV = 0.f;
    #pragma unroll
    for (int k = 0; k < 8; ++k) { sA += partA[b * 8 + k]; sV += partV[b * 8 + k]; }
    float mask = x[((size_t)b * 258 + 1) * 256 + t];
    out[b * 256 + t] = sV + oa - sA + mask * 10.0f;
}

extern "C" void kernel_launch(void* const* d_in, const int* in_sizes, int n_in,
                              void* d_out, int out_size, void* d_ws, size_t ws_size,
                              hipStream_t stream)
{
    (void)in_sizes; (void)n_in; (void)out_size; (void)ws_size;
    const float* x   = (const float*)d_in[0];
    const float* W0  = (const float*)d_in[1];
    const float* W1  = (const float*)d_in[2];
    const float* W2  = (const float*)d_in[3];
    const float* W3  = (const float*)d_in[4];
    const float* aw1 = (const float*)d_in[5];
    const float* ab1 = (const float*)d_in[6];
    const float* aw2 = (const float*)d_in[7];
    const float* ab2 = (const float*)d_in[8];
    const float* aw3 = (const float*)d_in[9];
    const float* ab3 = (const float*)d_in[10];
    const float* vw1 = (const float*)d_in[11];
    const float* vb1 = (const float*)d_in[12];
    const float* vw2 = (const float*)d_in[13];
    const float* vb2 = (const float*)d_in[14];

    float* ws    = (float*)d_ws;
    float* posg  = ws;                  // 4096
    float* negg  = ws + 4096;           // 4096
    float* oaw   = ws + 8192;           // 4096
    float* c2g   = ws + 12288;          // 1024
    float* P2g   = ws + 13312;          // 64
    float* N2g   = ws + 13376;          // 64
    float* partA = ws + 13440;          // 128
    float* partV = ws + 13568;          // 128
    int*   flagg = (int*)(ws + 13696);  // 16
    float* embg  = ws + 16384;          // 262144 (dirty path only)

    ka_embed<<<16, 1024, 0, stream>>>(x, W0, W1, W2, W3,
                                      posg, negg, c2g, P2g, N2g, flagg, embg);
    kb_heads<<<128, 256, 0, stream>>>(x, W0, posg, negg, c2g, P2g, N2g, flagg, embg,
                                      aw1, ab1, aw2, ab2, aw3, ab3,
                                      vw1, vb1, vw2, vb2, oaw, partA, partV);
    kc_final<<<16, 256, 0, stream>>>(x, oaw, partA, partV, (float*)d_out);
}

// Round 3
// 29.127 us; speedup vs baseline: 1.3366x; 1.2232x over previous
//
#include <hip/hip_runtime.h>

// DQN graph-embedding network, MI355X. B=16, A=256, UNITS=HID=64, T=3, fp32.
//
// Algebra (exact up to fp reassociation):
//   base[i,j]  = cs_i*W0_j + (pos_i*P2_j + neg_i*N2_j)/A, P2=relu(W3)@W2, N2=min(W3,0)@W2
//   emb_t[i,j] = relu(base[i,j] + c_t[j]),  c_{t+1} = (colsum(emb_t)/A)@W1,  c_0 = 0
//   (valid when weights have no exact zeros; per-batch ballot falls back to an
//    exact global-double-buffered path with per-row zero corrections.)
//
// K1 (128 blocks x 256 thr): block (batch=bid&15, sub=bid>>4) redundantly does
//   stats + P2/N2 + c-recurrence for its whole batch, then heads for its own
//   32 rows; writes out_a + per-block partial sums.  K2 (16 x 256): combine.

#define NB 16
#define NA 256
#define NU 64

__device__ __forceinline__ float reluf(float v) { return fmaxf(v, 0.f); }

// ---------------- K1: everything except the cross-block combine -------------------
__global__ __launch_bounds__(256) void k1_main(
    const float* __restrict__ x,
    const float* __restrict__ W0, const float* __restrict__ W1,
    const float* __restrict__ W2, const float* __restrict__ W3,
    const float* __restrict__ aw1, const float* __restrict__ ab1,
    const float* __restrict__ aw2, const float* __restrict__ ab2,
    const float* __restrict__ aw3, const float* __restrict__ ab3,
    const float* __restrict__ vw1, const float* __restrict__ vb1,
    const float* __restrict__ vw2, const float* __restrict__ vb2,
    float* __restrict__ oaw, float* __restrict__ partA, float* __restrict__ partV,
    float* __restrict__ embg)
{
    // bufA layout (floats): aw1s [0,4096) | vw1s [4096,8192) | aw2s stride33 [8192,10304)
    //                       embs 32x65   [10304,12384)
    __shared__ float bufA[12384];
    __shared__ float W1s[4096];
    __shared__ unsigned long long zmsL[1024];       // 4 words per row
    __shared__ float poss[256], negs[256], css[256];
    __shared__ float W0s[64], P2s[64], N2s[64], Ssh[64], e2c[64];
    __shared__ float wpart[256];
    __shared__ int   zrow[256];
    __shared__ int   zw[4];
    __shared__ float ab1s[64], vb1s[64], vw2s[64], ab2s[32], aw3s[32];
    __shared__ float ab3s[1], vb2s[1];
    __shared__ float soa[32], sov[32];

    const float invA = 1.0f / 256.0f;
    const int t = threadIdx.x;
    const int batch = blockIdx.x & 15;
    const int sub   = blockIdx.x >> 4;
    const int obase = sub * 32;                     // own 32 rows
    float* aw1s = bufA;
    float* vw1s = bufA + 4096;
    float* aw2s = bufA + 8192;                      // stride 33
    float* embs = bufA + 10304;                     // stride 65

    // ---- phase 0: stage weights to LDS (ordered before first use by SYNC1) ----
    #pragma unroll
    for (int k = 0; k < 4; ++k) {
        int idx = k * 1024 + t * 4;
        *(float4*)&aw1s[idx] = *(const float4*)&aw1[idx];
        *(float4*)&vw1s[idx] = *(const float4*)&vw1[idx];
        *(float4*)&W1s[idx]  = *(const float4*)&W1[idx];
    }
    #pragma unroll
    for (int k = 0; k < 8; ++k) {
        int idx = k * 256 + t;
        aw2s[(idx >> 5) * 33 + (idx & 31)] = aw2[idx];
    }
    if (t < 64) { W0s[t] = W0[t]; ab1s[t] = ab1[t]; vb1s[t] = vb1[t]; vw2s[t] = vw2[t]; }
    if (t >= 64 && t < 96) { ab2s[t - 64] = ab2[t - 64]; aw3s[t - 64] = aw3[t - 64]; }
    if (t == 96) { ab3s[0] = ab3[0]; vb2s[0] = vb2[0]; }

    // ---- phase 1: stats for ALL 256 rows of this batch (4 passes, quad/row) ----
    {
        const int r4 = t >> 2, sub4 = t & 3;
        #pragma unroll
        for (int p = 0; p < 4; ++p) {
            int row = p * 64 + r4;
            const float* rowp = x + ((size_t)batch * 258 + 2 + row) * 256 + sub4 * 64;
            float pp = 0.f, nn = 0.f;
            unsigned long long zm = 0ull;
            #pragma unroll
            for (int c = 0; c < 64; c += 4) {
                float4 v = *(const float4*)(rowp + c);
                pp += fmaxf(v.x, 0.f) + fmaxf(v.y, 0.f) + fmaxf(v.z, 0.f) + fmaxf(v.w, 0.f);
                nn += fminf(v.x, 0.f) + fminf(v.y, 0.f) + fminf(v.z, 0.f) + fminf(v.w, 0.f);
                if (v.x == 0.f) zm |= 1ull << (c + 0);
                if (v.y == 0.f) zm |= 1ull << (c + 1);
                if (v.z == 0.f) zm |= 1ull << (c + 2);
                if (v.w == 0.f) zm |= 1ull << (c + 3);
            }
            zmsL[row * 4 + sub4] = zm;
            int zf = (zm != 0ull);
            pp += __shfl_xor(pp, 1); pp += __shfl_xor(pp, 2);
            nn += __shfl_xor(nn, 1); nn += __shfl_xor(nn, 2);
            zf |= __shfl_xor(zf, 1); zf |= __shfl_xor(zf, 2);
            if (sub4 == 0) { poss[row] = pp; negs[row] = nn; zrow[row] = zf; }
        }
        css[t] = x[(size_t)batch * 66048 + t];      // cur_sol
    }

    // ---- phase 2: P2/N2 partials (4 m-groups x 64 cols) ----
    {
        int j = t & 63, mg = t >> 6;
        float pa = 0.f, na = 0.f;
        #pragma unroll
        for (int k = 0; k < 16; ++k) {
            int m = mg * 16 + k;
            float w3 = W3[m];                        // uniform -> scalar load
            float w2 = W2[m * 64 + j];
            pa = fmaf(fmaxf(w3, 0.f), w2, pa);
            na = fmaf(fminf(w3, 0.f), w2, na);
        }
        wpart[mg * 64 + j] = pa;
        negs[256 - 256]; // no-op
        // store na via second array slot: reuse soa/sov too small; use Ssh trick:
        // instead accumulate na into zmsL-safe float area: use e2c as temp
        e2c[0] = e2c[0]; // placeholder (na handled below via second wpart round)
        __syncthreads();                             // SYNC1a: wpart(pa) visible
        if (t < 64) {
            float P2 = wpart[t] + wpart[64 + t] + wpart[128 + t] + wpart[192 + t];
            P2s[t] = P2;
        }
        __syncthreads();                             // SYNC1b
        wpart[mg * 64 + j] = na;
        __syncthreads();                             // SYNC1c: wpart(na) visible
        if (t < 64) {
            float N2 = wpart[t] + wpart[64 + t] + wpart[128 + t] + wpart[192 + t];
            N2s[t] = N2;
        }
        // dirty ballot
        int zf = zrow[t];
        unsigned long long ball = __ballot(zf != 0);
        if ((t & 63) == 0) zw[t >> 6] = (ball != 0ull) ? 1 : 0;
    }
    __syncthreads();                                 // SYNC2: P2s/N2s/zw visible
    const int dirty = zw[0] | zw[1] | zw[2] | zw[3];

    if (!dirty) {
        // ---- fast path: 2 colsum->matvec rounds, nothing materialized ----
        const int j = t & 63, rg = t >> 6;
        const float w0j = W0s[j], p2j = P2s[j], n2j = N2s[j];
        float c_j = 0.f;
        #pragma unroll
        for (int iter = 0; iter < 2; ++iter) {
            float s = 0.f;
            #pragma unroll 8
            for (int k = 0; k < 64; ++k) {
                int i = rg * 64 + k;
                s += reluf(fmaf(css[i], w0j, (poss[i] * p2j + negs[i] * n2j) * invA) + c_j);
            }
            wpart[rg * 64 + j] = s;
            __syncthreads();
            if (t < 64) {
                float S = wpart[t] + wpart[64 + t] + wpart[128 + t] + wpart[192 + t];
                Ssh[t] = S;                           // wave0-internal exchange
                float c = 0.f;
                #pragma unroll 8
                for (int m = 0; m < 64; ++m) c = fmaf(Ssh[m], W1s[m * 64 + t], c);
                e2c[t] = c * invA;
            }
            __syncthreads();
            c_j = e2c[j];
        }
        // own 32 rows -> embs (stride 65)
        #pragma unroll
        for (int k = 0; k < 8; ++k) {
            int idx = k * 256 + t;
            int il = idx >> 6, j2 = idx & 63;
            int row = obase + il;
            embs[il * 65 + j2] = reluf(fmaf(css[row], W0s[j2],
                                 (poss[row] * P2s[j2] + negs[row] * N2s[j2]) * invA)
                                 + e2c[j2]);
        }
    } else {
        // ---- exact slow path: global double-buffer + per-row zero corrections ----
        float* eb0 = embg + (size_t)blockIdx.x * 32768;
        float* eb1 = eb0 + 16384;
        const int r4 = t >> 2, sub4 = t & 3, jb = sub4 * 16;
        // iter 0: emb1 = relu(base)
        #pragma unroll
        for (int p = 0; p < 4; ++p) {
            int row = p * 64 + r4;
            float cs = css[row], pi = poss[row], ni = negs[row];
            #pragma unroll
            for (int q = 0; q < 16; ++q) {
                int jj = jb + q;
                eb0[row * 64 + jj] = reluf(fmaf(cs, W0s[jj],
                                      (pi * P2s[jj] + ni * N2s[jj]) * invA));
            }
        }
        __syncthreads();
        float* cur = eb0; float* nxt = eb1;
        for (int it = 1; it <= 2; ++it) {
            // colsum of cur
            {
                int j = t & 63, rg = t >> 6;
                float s = 0.f;
                for (int k = 0; k < 64; ++k) s += cur[(rg * 64 + k) * 64 + j];
                wpart[rg * 64 + j] = s;
            }
            __syncthreads();
            if (t < 64) {
                float S = wpart[t] + wpart[64 + t] + wpart[128 + t] + wpart[192 + t];
                Ssh[t] = S;
                float c = 0.f;
                for (int m = 0; m < 64; ++m) c = fmaf(Ssh[m], W1s[m * 64 + t], c);
                e2c[t] = c * invA;
            }
            __syncthreads();
            // rows with corrections
            #pragma unroll
            for (int p = 0; p < 4; ++p) {
                int row = p * 64 + r4;
                float cs = css[row], pi = poss[row], ni = negs[row];
                float acc[16];
                #pragma unroll
                for (int q = 0; q < 16; ++q) {
                    int jj = jb + q;
                    acc[q] = fmaf(cs, W0s[jj], (pi * P2s[jj] + ni * N2s[jj]) * invA)
                             + e2c[jj];
                }
                if (zrow[row]) {
                    for (int wd = 0; wd < 4; ++wd) {
                        unsigned long long zm = zmsL[row * 4 + wd];
                        while (zm) {
                            int k = wd * 64 + __builtin_ctzll(zm);
                            zm &= zm - 1;
                            float corr[16];
                            #pragma unroll
                            for (int q = 0; q < 16; ++q) corr[q] = 0.f;
                            for (int m = 0; m < 64; ++m) {
                                float ebm = cur[k * 64 + m];
                                #pragma unroll
                                for (int q = 0; q < 16; ++q)
                                    corr[q] = fmaf(ebm, W1s[m * 64 + jb + q], corr[q]);
                            }
                            #pragma unroll
                            for (int q = 0; q < 16; ++q) acc[q] -= corr[q] * invA;
                        }
                    }
                }
                #pragma unroll
                for (int q = 0; q < 16; ++q)
                    nxt[row * 64 + jb + q] = reluf(acc[q]);
            }
            __syncthreads();
            float* tmp = cur; cur = nxt; nxt = tmp;
        }
        // own rows from cur -> embs
        #pragma unroll
        for (int k = 0; k < 8; ++k) {
            int idx = k * 256 + t;
            int il = idx >> 6, j2 = idx & 63;
            embs[il * 65 + j2] = cur[(obase + il) * 64 + j2];
        }
    }
    __syncthreads();                                 // embs ready

    // ---- heads: 32 rows, 8 threads per row ----
    const int lr = t >> 3;
    const int jb = (t & 7) * 8;

    float h1[8], hv[8];
    #pragma unroll
    for (int q = 0; q < 8; ++q) { h1[q] = ab1s[jb + q]; hv[q] = vb1s[jb + q]; }

    for (int m = 0; m < 64; ++m) {
        float em = embs[lr * 65 + m];
        const float4 a0 = *(const float4*)&aw1s[m * 64 + jb];
        const float4 a1 = *(const float4*)&aw1s[m * 64 + jb + 4];
        const float4 b0 = *(const float4*)&vw1s[m * 64 + jb];
        const float4 b1 = *(const float4*)&vw1s[m * 64 + jb + 4];
        h1[0] = fmaf(em, a0.x, h1[0]); h1[1] = fmaf(em, a0.y, h1[1]);
        h1[2] = fmaf(em, a0.z, h1[2]); h1[3] = fmaf(em, a0.w, h1[3]);
        h1[4] = fmaf(em, a1.x, h1[4]); h1[5] = fmaf(em, a1.y, h1[5]);
        h1[6] = fmaf(em, a1.z, h1[6]); h1[7] = fmaf(em, a1.w, h1[7]);
        hv[0] = fmaf(em, b0.x, hv[0]); hv[1] = fmaf(em, b0.y, hv[1]);
        hv[2] = fmaf(em, b0.z, hv[2]); hv[3] = fmaf(em, b0.w, hv[3]);
        hv[4] = fmaf(em, b1.x, hv[4]); hv[5] = fmaf(em, b1.y, hv[5]);
        hv[6] = fmaf(em, b1.z, hv[6]); hv[7] = fmaf(em, b1.w, hv[7]);
    }

    float ovp = 0.f;
    #pragma unroll
    for (int q = 0; q < 8; ++q) {
        h1[q] = reluf(h1[q]);
        hv[q] = reluf(hv[q]);
        ovp = fmaf(hv[q], vw2s[jb + q], ovp);
    }
    ovp += __shfl_xor(ovp, 1); ovp += __shfl_xor(ovp, 2); ovp += __shfl_xor(ovp, 4);

    float h2p[32];
    #pragma unroll
    for (int j2 = 0; j2 < 32; ++j2) h2p[j2] = 0.f;
    #pragma unroll
    for (int q = 0; q < 8; ++q) {
        float h = h1[q];
        int rr = jb + q;
        #pragma unroll
        for (int j2 = 0; j2 < 32; ++j2) h2p[j2] = fmaf(h, aw2s[rr * 33 + j2], h2p[j2]);
    }
    #pragma unroll
    for (int j2 = 0; j2 < 32; ++j2) {
        float s = h2p[j2];
        s += __shfl_xor(s, 1); s += __shfl_xor(s, 2); s += __shfl_xor(s, 4);
        h2p[j2] = s;
    }

    if ((t & 7) == 0) {
        float oa = ab3s[0];
        #pragma unroll
        for (int j2 = 0; j2 < 32; ++j2)
            oa = fmaf(reluf(h2p[j2] + ab2s[j2]), aw3s[j2], oa);
        oaw[batch * 256 + obase + lr] = oa;
        soa[lr] = oa;
        sov[lr] = ovp + vb2s[0];
    }
    __syncthreads();
    if (t < 32) {
        float a = soa[t], v = sov[t];
        a += __shfl_xor(a, 1); a += __shfl_xor(a, 2); a += __shfl_xor(a, 4);
        a += __shfl_xor(a, 8); a += __shfl_xor(a, 16);
        v += __shfl_xor(v, 1); v += __shfl_xor(v, 2); v += __shfl_xor(v, 4);
        v += __shfl_xor(v, 8); v += __shfl_xor(v, 16);
        if (t == 0) { partA[blockIdx.x] = a; partV[blockIdx.x] = v; }
    }
}

// ---------------- K2: final combine ----------------------------------------------
__global__ __launch_bounds__(256) void k2_final(const float* __restrict__ x,
                                                const float* __restrict__ oaw,
                                                const float* __restrict__ partA,
                                                const float* __restrict__ partV,
                                                float* __restrict__ out)
{
    int b = blockIdx.x, t = threadIdx.x;
    float oa = oaw[b * 256 + t];
    float sA = 0.f, sV = 0.f;
    #pragma unroll
    for (int k = 0; k < 8; ++k) { sA += partA[k * 16 + b]; sV += partV[k * 16 + b]; }
    float mask = x[((size_t)b * 258 + 1) * 256 + t];
    out[b * 256 + t] = sV + oa - sA + mask * 10.0f;
}

extern "C" void kernel_launch(void* const* d_in, const int* in_sizes, int n_in,
                              void* d_out, int out_size, void* d_ws, size_t ws_size,
                              hipStream_t stream)
{
    (void)in_sizes; (void)n_in; (void)out_size; (void)ws_size;
    const float* x   = (const float*)d_in[0];
    const float* W0  = (const float*)d_in[1];
    const float* W1  = (const float*)d_in[2];
    const float* W2  = (const float*)d_in[3];
    const float* W3  = (const float*)d_in[4];
    const float* aw1 = (const float*)d_in[5];
    const float* ab1 = (const float*)d_in[6];
    const float* aw2 = (const float*)d_in[7];
    const float* ab2 = (const float*)d_in[8];
    const float* aw3 = (const float*)d_in[9];
    const float* ab3 = (const float*)d_in[10];
    const float* vw1 = (const float*)d_in[11];
    const float* vb1 = (const float*)d_in[12];
    const float* vw2 = (const float*)d_in[13];
    const float* vb2 = (const float*)d_in[14];

    float* ws    = (float*)d_ws;
    float* oaw   = ws;                  // 4096
    float* partA = ws + 4096;           // 128
    float* partV = ws + 4224;           // 128
    float* embg  = ws + 8192;           // 128 blocks * 32768 (dirty path only)

    k1_main<<<128, 256, 0, stream>>>(x, W0, W1, W2, W3,
                                     aw1, ab1, aw2, ab2, aw3, ab3,
                                     vw1, vb1, vw2, vb2,
                                     oaw, partA, partV, embg);
    k2_final<<<16, 256, 0, stream>>>(x, oaw, partA, partV, (float*)d_out);
}